// Round 1
// baseline (737.479 us; speedup 1.0000x reference)
//
#include <hip/hip_runtime.h>

#define Bc 2
#define Sc 2048
#define Dc 2048
#define Hc 16
#define HDc 128
#define Mc 4096

typedef __bf16 bf16_t;
typedef __bf16 bf16x4 __attribute__((ext_vector_type(4)));
typedef __bf16 bf16x8 __attribute__((ext_vector_type(8)));
typedef float f32x4 __attribute__((ext_vector_type(4)));

__device__ __forceinline__ f32x4 mfma16(bf16x8 a, bf16x8 b, f32x4 c) {
  return __builtin_amdgcn_mfma_f32_16x16x32_bf16(a, b, c, 0, 0, 0);
}

typedef const unsigned __attribute__((address_space(1))) gu32_t;
typedef unsigned __attribute__((address_space(3))) lu32_t;

__device__ __forceinline__ void gload_lds16(const void* g, void* l) {
  gu32_t* gp = (gu32_t*)(unsigned long long)g;
  lu32_t* lp = (lu32_t*)(unsigned)(unsigned long long)l;
  __builtin_amdgcn_global_load_lds(gp, lp, 16, 0, 0);
}

// ---------------- convert x: fp32 -> bf16 ----------------
__global__ void cvt_bf16_kernel(const float* __restrict__ in, bf16_t* __restrict__ out, int n4) {
  int i = blockIdx.x * blockDim.x + threadIdx.x;
  if (i < n4) {
    float4 v = ((const float4*)in)[i];
    bf16x4 o;
    o[0] = (bf16_t)v.x; o[1] = (bf16_t)v.y; o[2] = (bf16_t)v.z; o[3] = (bf16_t)v.w;
    ((bf16x4*)out)[i] = o;
  }
}

// ---------------- transpose-convert weight: (K,N) fp32 -> (N,K) bf16 ----------------
__global__ void transpose_cvt_kernel(const float* __restrict__ w, bf16_t* __restrict__ wt) {
  __shared__ float tile[32][33];
  const int tx = threadIdx.x, ty = threadIdx.y;
  const int n0 = blockIdx.x * 32, k0 = blockIdx.y * 32;
#pragma unroll
  for (int i = 0; i < 32; i += 8)
    tile[ty + i][tx] = w[(size_t)(k0 + ty + i) * Dc + n0 + tx];
  __syncthreads();
#pragma unroll
  for (int i = 0; i < 32; i += 8)
    wt[(size_t)(n0 + ty + i) * Dc + k0 + tx] = (bf16_t)tile[tx][ty + i];
}

// ---------------- GEMM: C(MxN) = A(MxK) @ Bt(NxK)^T + bias ----------------
// MODE 0: write bf16 to (B,H,S,HD) layout (Q/K pre-rope)
// MODE 1: write bf16 to (B,H,HD,S) layout (V transposed)
// MODE 2: write fp32 to (M,N) row-major (final output)
template <int MODE>
__global__ __launch_bounds__(256) void gemm_bt_kernel(
    const bf16_t* __restrict__ A, const bf16_t* __restrict__ Bt,
    const float* __restrict__ bias, void* __restrict__ outp, const int K) {
  __shared__ __align__(16) bf16_t sA[128 * 64];
  __shared__ __align__(16) bf16_t sB[128 * 64];
  const int w = threadIdx.x >> 6, lane = threadIdx.x & 63;
  const int l15 = lane & 15, g = lane >> 4;
  const int m0 = blockIdx.y * 128, n0 = blockIdx.x * 128;

  f32x4 acc[4][4] = {};

  for (int k0 = 0; k0 < K; k0 += 64) {
#pragma unroll
    for (int p = 0; p < 4; ++p) {
      int s_ = (p * 4 + w) * 64 + lane;
      int row = s_ >> 3, ch = s_ & 7;
      int sch = (ch ^ (row & 7)) * 8;  // source-side swizzle, elements
      gload_lds16(A + (size_t)(m0 + row) * K + k0 + sch,
                  (char*)sA + (size_t)((p * 4 + w) * 64) * 16);
      gload_lds16(Bt + (size_t)(n0 + row) * K + k0 + sch,
                  (char*)sB + (size_t)((p * 4 + w) * 64) * 16);
    }
    asm volatile("s_waitcnt vmcnt(0)" ::: "memory");
    __syncthreads();

    const int wm = (w >> 1) * 64, wn = (w & 1) * 64;
#pragma unroll
    for (int ks = 0; ks < 2; ++ks) {
      bf16x8 af[4], bfr[4];
#pragma unroll
      for (int i = 0; i < 4; ++i) {
        int ra = wm + i * 16 + l15;
        int ca = ((ks * 4 + g) ^ (ra & 7)) * 16;
        af[i] = *(const bf16x8*)((const char*)sA + ra * 128 + ca);
        int rb = wn + i * 16 + l15;
        int cb = ((ks * 4 + g) ^ (rb & 7)) * 16;
        bfr[i] = *(const bf16x8*)((const char*)sB + rb * 128 + cb);
      }
#pragma unroll
      for (int mi = 0; mi < 4; ++mi)
#pragma unroll
        for (int ni = 0; ni < 4; ++ni)
          acc[mi][ni] = mfma16(af[mi], bfr[ni], acc[mi][ni]);
    }
    __syncthreads();
  }

  const int wm = (w >> 1) * 64, wn = (w & 1) * 64;
#pragma unroll
  for (int mi = 0; mi < 4; ++mi) {
#pragma unroll
    for (int ni = 0; ni < 4; ++ni) {
      int ncol = n0 + wn + ni * 16 + l15;
      float bv = bias[ncol];
#pragma unroll
      for (int r = 0; r < 4; ++r) {
        int mrow = m0 + wm + mi * 16 + g * 4 + r;
        float v = acc[mi][ni][r] + bv;
        if (MODE == 2) {
          ((float*)outp)[(size_t)mrow * Dc + ncol] = v;
        } else {
          int b = mrow >> 11, sq = mrow & (Sc - 1);
          int h = ncol >> 7, hd = ncol & (HDc - 1);
          if (MODE == 0)
            ((bf16_t*)outp)[(((size_t)(b * Hc + h) * Sc + sq) * HDc) + hd] = (bf16_t)v;
          else
            ((bf16_t*)outp)[(((size_t)(b * Hc + h) * HDc + hd) * Sc) + sq] = (bf16_t)v;
        }
      }
    }
  }
}

// ---------------- RoPE in-place on Q then K region (contiguous), (B,H,S,HD) ----------------
__global__ __launch_bounds__(256) void rope_kernel(bf16_t* __restrict__ qk) {
  const int w = threadIdx.x >> 6, lane = threadIdx.x & 63;
  const long row = (long)blockIdx.x * 4 + w;  // 0 .. 2*B*H*S-1
  const int s = (int)(row & (Sc - 1));
  bf16_t* p = qk + row * HDc;
  float x1 = (float)p[2 * lane];
  float x2 = (float)p[2 * lane + 1];
  // inv_freq = 10000^(-lane/64); ln(10000)=9.210340371976184
  float freq = expf(-(float)lane * (9.210340371976184f / 64.0f));
  float ang = (float)s * freq;
  float sn, cs;
  sincosf(ang, &sn, &cs);
  __syncthreads();
  p[lane] = (bf16_t)(x1 * cs - x2 * sn);
  p[lane + 64] = (bf16_t)(x1 * sn + x2 * cs);
}

// ---------------- flash attention ----------------
// grid: B*H*(S/64); block 256 = 4 waves; wave handles 16 q-rows
__global__ __launch_bounds__(256) void attn_kernel(
    const bf16_t* __restrict__ Q, const bf16_t* __restrict__ Kr,
    const bf16_t* __restrict__ Vt, const int* __restrict__ mask,
    bf16_t* __restrict__ AO) {
  __shared__ bf16_t plds[4 * 16 * 40];
  const int w = threadIdx.x >> 6, lane = threadIdx.x & 63;
  const int l15 = lane & 15, g = lane >> 4;
  const int bx = blockIdx.x;
  const int qt = bx & 31, h = (bx >> 5) & 15, b = bx >> 9;
  const int sq0 = qt * 64 + w * 16;
  const bf16_t* qb = Q + ((size_t)(b * Hc + h) * Sc) * HDc;
  const bf16_t* kb = Kr + ((size_t)(b * Hc + h) * Sc) * HDc;
  const bf16_t* vb = Vt + ((size_t)(b * Hc + h) * HDc) * Sc;
  const int* mb = mask + b * Sc;
  bf16_t* pl = plds + w * 640;

  bf16x8 aq[4];
  {
    const bf16_t* qrow = qb + (size_t)(sq0 + l15) * HDc + g * 8;
#pragma unroll
    for (int kc = 0; kc < 4; ++kc) aq[kc] = *(const bf16x8*)(qrow + kc * 32);
  }

  f32x4 acc[8] = {};
  float mrun[4], lrun[4];
#pragma unroll
  for (int r = 0; r < 4; ++r) { mrun[r] = -3.0e38f; lrun[r] = 0.f; }

  const float scale = 0.08838834764831845f;  // 128^-0.5

  for (int k0 = 0; k0 < Sc; k0 += 32) {
    f32x4 s0 = {0.f, 0.f, 0.f, 0.f}, s1 = {0.f, 0.f, 0.f, 0.f};
    const bf16_t* kr0 = kb + (size_t)(k0 + l15) * HDc + g * 8;
    const bf16_t* kr1 = kr0 + 16 * HDc;
#pragma unroll
    for (int kc = 0; kc < 4; ++kc) {
      s0 = mfma16(aq[kc], *(const bf16x8*)(kr0 + kc * 32), s0);
      s1 = mfma16(aq[kc], *(const bf16x8*)(kr1 + kc * 32), s1);
    }
    const float bias0 = (mb[k0 + l15] == 0) ? -1e9f : 0.f;
    const float bias1 = (mb[k0 + 16 + l15] == 0) ? -1e9f : 0.f;
#pragma unroll
    for (int r = 0; r < 4; ++r) {
      float v0 = s0[r] * scale + bias0;
      float v1 = s1[r] * scale + bias1;
      float mx = fmaxf(v0, v1);
      mx = fmaxf(mx, __shfl_xor(mx, 1));
      mx = fmaxf(mx, __shfl_xor(mx, 2));
      mx = fmaxf(mx, __shfl_xor(mx, 4));
      mx = fmaxf(mx, __shfl_xor(mx, 8));
      float mnew = fmaxf(mrun[r], mx);
      float al = expf(mrun[r] - mnew);
      float p0 = expf(v0 - mnew);
      float p1 = expf(v1 - mnew);
      float sum = p0 + p1;
      sum += __shfl_xor(sum, 1);
      sum += __shfl_xor(sum, 2);
      sum += __shfl_xor(sum, 4);
      sum += __shfl_xor(sum, 8);
      lrun[r] = lrun[r] * al + sum;
      mrun[r] = mnew;
#pragma unroll
      for (int df = 0; df < 8; ++df) acc[df][r] *= al;
      pl[(g * 4 + r) * 40 + l15] = (bf16_t)p0;
      pl[(g * 4 + r) * 40 + 16 + l15] = (bf16_t)p1;
    }
    asm volatile("s_waitcnt lgkmcnt(0)" ::: "memory");
    __builtin_amdgcn_sched_barrier(0);
    bf16x8 ap = *(const bf16x8*)(pl + l15 * 40 + g * 8);
#pragma unroll
    for (int df = 0; df < 8; ++df) {
      bf16x8 bv = *(const bf16x8*)(vb + (size_t)(df * 16 + l15) * Sc + k0 + g * 8);
      acc[df] = mfma16(ap, bv, acc[df]);
    }
    asm volatile("s_waitcnt lgkmcnt(0)" ::: "memory");
    __builtin_amdgcn_sched_barrier(0);
  }

  float inv[4];
#pragma unroll
  for (int r = 0; r < 4; ++r) inv[r] = 1.f / lrun[r];
  const size_t obase = ((size_t)b * Sc) * Dc + (size_t)h * HDc;
#pragma unroll
  for (int df = 0; df < 8; ++df) {
#pragma unroll
    for (int r = 0; r < 4; ++r) {
      int sq = sq0 + g * 4 + r;
      int d = df * 16 + l15;
      AO[obase + (size_t)sq * Dc + d] = (bf16_t)(acc[df][r] * inv[r]);
    }
  }
}

#define MB(x) ((size_t)(x) << 20)

extern "C" void kernel_launch(void* const* d_in, const int* in_sizes, int n_in,
                              void* d_out, int out_size, void* d_ws, size_t ws_size,
                              hipStream_t stream) {
  const float* x = (const float*)d_in[0];
  const int* mask = (const int*)d_in[1];
  const float* wq = (const float*)d_in[2];
  const float* bq = (const float*)d_in[3];
  const float* wk = (const float*)d_in[4];
  const float* bk = (const float*)d_in[5];
  const float* wv = (const float*)d_in[6];
  const float* bv = (const float*)d_in[7];
  const float* wo = (const float*)d_in[8];
  const float* bo = (const float*)d_in[9];
  float* out = (float*)d_out;

  char* ws = (char*)d_ws;
  bf16_t* xb  = (bf16_t*)(ws + MB(0));    // 16 MB  : x bf16 (M x D)
  bf16_t* wqT = (bf16_t*)(ws + MB(16));   // 8 MB   : wq^T bf16 (N x K)
  bf16_t* wkT = (bf16_t*)(ws + MB(24));
  bf16_t* wvT = (bf16_t*)(ws + MB(32));
  bf16_t* woT = (bf16_t*)(ws + MB(40));
  bf16_t* qbuf = (bf16_t*)(ws + MB(48));  // 16 MB : Q (B,H,S,HD)
  bf16_t* kbuf = (bf16_t*)(ws + MB(64));  // 16 MB : K (B,H,S,HD)  (contiguous after Q)
  bf16_t* vtb  = (bf16_t*)(ws + MB(80));  // 16 MB : V^T (B,H,HD,S)
  bf16_t* ao   = (bf16_t*)(ws + MB(96));  // 16 MB : attn out (M x D)

  // 1. convert x to bf16
  cvt_bf16_kernel<<<8192, 256, 0, stream>>>(x, xb, (Mc * Dc) / 4);

  // 2. transpose-convert weights
  dim3 tg(64, 64), tb(32, 8);
  transpose_cvt_kernel<<<tg, tb, 0, stream>>>(wq, wqT);
  transpose_cvt_kernel<<<tg, tb, 0, stream>>>(wk, wkT);
  transpose_cvt_kernel<<<tg, tb, 0, stream>>>(wv, wvT);
  transpose_cvt_kernel<<<tg, tb, 0, stream>>>(wo, woT);

  // 3. QKV projections
  dim3 gg(Dc / 128, Mc / 128);
  gemm_bt_kernel<0><<<gg, 256, 0, stream>>>(xb, wqT, bq, qbuf, Dc);
  gemm_bt_kernel<0><<<gg, 256, 0, stream>>>(xb, wkT, bk, kbuf, Dc);
  gemm_bt_kernel<1><<<gg, 256, 0, stream>>>(xb, wvT, bv, vtb, Dc);

  // 4. RoPE in-place on Q and K (contiguous 2*B*H*S rows of HD)
  rope_kernel<<<(2 * Bc * Hc * Sc) / 4, 256, 0, stream>>>(qbuf);

  // 5. attention
  attn_kernel<<<Bc * Hc * (Sc / 64), 256, 0, stream>>>(qbuf, kbuf, vtb, mask, ao);

  // 6. output projection (fp32 out)
  gemm_bt_kernel<2><<<gg, 256, 0, stream>>>(ao, woT, bo, out, Dc);
}

// Round 2
// 490.233 us; speedup vs baseline: 1.5043x; 1.5043x over previous
//
#include <hip/hip_runtime.h>

#define Bc 2
#define Sc 2048
#define Dc 2048
#define Hc 16
#define HDc 128
#define Mc 4096

typedef __bf16 bf16_t;
typedef __bf16 bf16x4 __attribute__((ext_vector_type(4)));
typedef __bf16 bf16x8 __attribute__((ext_vector_type(8)));
typedef float f32x4 __attribute__((ext_vector_type(4)));
typedef float f32x16 __attribute__((ext_vector_type(16)));

__device__ __forceinline__ f32x4 mfma16(bf16x8 a, bf16x8 b, f32x4 c) {
  return __builtin_amdgcn_mfma_f32_16x16x32_bf16(a, b, c, 0, 0, 0);
}
__device__ __forceinline__ f32x16 mfma32(bf16x8 a, bf16x8 b, f32x16 c) {
  return __builtin_amdgcn_mfma_f32_32x32x16_bf16(a, b, c, 0, 0, 0);
}

typedef const unsigned __attribute__((address_space(1))) gu32_t;
typedef unsigned __attribute__((address_space(3))) lu32_t;

__device__ __forceinline__ void gload_lds16(const void* g, void* l) {
  gu32_t* gp = (gu32_t*)(unsigned long long)g;
  lu32_t* lp = (lu32_t*)(unsigned)(unsigned long long)l;
  __builtin_amdgcn_global_load_lds(gp, lp, 16, 0, 0);
}

__device__ __forceinline__ unsigned cvtpk(float lo, float hi_) {
  unsigned r;
  asm("v_cvt_pk_bf16_f32 %0, %1, %2" : "=v"(r) : "v"(lo), "v"(hi_));
  return r;
}
__device__ __forceinline__ void plswap(unsigned& a, unsigned& b) {
  // exchanges a[lanes 32..63] <-> b[lanes 0..31]
  asm volatile("v_permlane32_swap_b32 %0, %1" : "+v"(a), "+v"(b));
}

// ---------------- convert x: fp32 -> bf16 ----------------
__global__ void cvt_bf16_kernel(const float* __restrict__ in, bf16_t* __restrict__ out, int n4) {
  int i = blockIdx.x * blockDim.x + threadIdx.x;
  if (i < n4) {
    float4 v = ((const float4*)in)[i];
    bf16x4 o;
    o[0] = (bf16_t)v.x; o[1] = (bf16_t)v.y; o[2] = (bf16_t)v.z; o[3] = (bf16_t)v.w;
    ((bf16x4*)out)[i] = o;
  }
}

// ---------------- transpose-convert weight: (K,N) fp32 -> (N,K) bf16 ----------------
__global__ void transpose_cvt_kernel(const float* __restrict__ w, bf16_t* __restrict__ wt) {
  __shared__ float tile[32][33];
  const int tx = threadIdx.x, ty = threadIdx.y;
  const int n0 = blockIdx.x * 32, k0 = blockIdx.y * 32;
#pragma unroll
  for (int i = 0; i < 32; i += 8)
    tile[ty + i][tx] = w[(size_t)(k0 + ty + i) * Dc + n0 + tx];
  __syncthreads();
#pragma unroll
  for (int i = 0; i < 32; i += 8)
    wt[(size_t)(n0 + ty + i) * Dc + k0 + tx] = (bf16_t)tile[tx][ty + i];
}

// ---------------- GEMM: C(MxN) = A(MxK) @ Bt(NxK)^T + bias ----------------
template <int MODE>
__global__ __launch_bounds__(256) void gemm_bt_kernel(
    const bf16_t* __restrict__ A, const bf16_t* __restrict__ Bt,
    const float* __restrict__ bias, void* __restrict__ outp, const int K) {
  __shared__ __align__(16) bf16_t sA[128 * 64];
  __shared__ __align__(16) bf16_t sB[128 * 64];
  const int w = threadIdx.x >> 6, lane = threadIdx.x & 63;
  const int l15 = lane & 15, g = lane >> 4;
  const int m0 = blockIdx.y * 128, n0 = blockIdx.x * 128;

  f32x4 acc[4][4] = {};

  for (int k0 = 0; k0 < K; k0 += 64) {
#pragma unroll
    for (int p = 0; p < 4; ++p) {
      int s_ = (p * 4 + w) * 64 + lane;
      int row = s_ >> 3, ch = s_ & 7;
      int sch = (ch ^ (row & 7)) * 8;
      gload_lds16(A + (size_t)(m0 + row) * K + k0 + sch,
                  (char*)sA + (size_t)((p * 4 + w) * 64) * 16);
      gload_lds16(Bt + (size_t)(n0 + row) * K + k0 + sch,
                  (char*)sB + (size_t)((p * 4 + w) * 64) * 16);
    }
    asm volatile("s_waitcnt vmcnt(0)" ::: "memory");
    __syncthreads();

    const int wm = (w >> 1) * 64, wn = (w & 1) * 64;
#pragma unroll
    for (int ks = 0; ks < 2; ++ks) {
      bf16x8 af[4], bfr[4];
#pragma unroll
      for (int i = 0; i < 4; ++i) {
        int ra = wm + i * 16 + l15;
        int ca = ((ks * 4 + g) ^ (ra & 7)) * 16;
        af[i] = *(const bf16x8*)((const char*)sA + ra * 128 + ca);
        int rb = wn + i * 16 + l15;
        int cb = ((ks * 4 + g) ^ (rb & 7)) * 16;
        bfr[i] = *(const bf16x8*)((const char*)sB + rb * 128 + cb);
      }
#pragma unroll
      for (int mi = 0; mi < 4; ++mi)
#pragma unroll
        for (int ni = 0; ni < 4; ++ni)
          acc[mi][ni] = mfma16(af[mi], bfr[ni], acc[mi][ni]);
    }
    __syncthreads();
  }

  const int wm = (w >> 1) * 64, wn = (w & 1) * 64;
#pragma unroll
  for (int mi = 0; mi < 4; ++mi) {
#pragma unroll
    for (int ni = 0; ni < 4; ++ni) {
      int ncol = n0 + wn + ni * 16 + l15;
      float bv = bias[ncol];
#pragma unroll
      for (int r = 0; r < 4; ++r) {
        int mrow = m0 + wm + mi * 16 + g * 4 + r;
        float v = acc[mi][ni][r] + bv;
        if (MODE == 2) {
          ((float*)outp)[(size_t)mrow * Dc + ncol] = v;
        } else {
          int b = mrow >> 11, sq = mrow & (Sc - 1);
          int h = ncol >> 7, hd = ncol & (HDc - 1);
          if (MODE == 0)
            ((bf16_t*)outp)[(((size_t)(b * Hc + h) * Sc + sq) * HDc) + hd] = (bf16_t)v;
          else
            ((bf16_t*)outp)[(((size_t)(b * Hc + h) * HDc + hd) * Sc) + sq] = (bf16_t)v;
        }
      }
    }
  }
}

// ---------------- RoPE in-place on Q then K region (contiguous), (B,H,S,HD) ----------------
__global__ __launch_bounds__(256) void rope_kernel(bf16_t* __restrict__ qk) {
  const int w = threadIdx.x >> 6, lane = threadIdx.x & 63;
  const long row = (long)blockIdx.x * 4 + w;
  const int s = (int)(row & (Sc - 1));
  bf16_t* p = qk + row * HDc;
  float x1 = (float)p[2 * lane];
  float x2 = (float)p[2 * lane + 1];
  float freq = expf(-(float)lane * (9.210340371976184f / 64.0f));
  float ang = (float)s * freq;
  float sn, cs;
  sincosf(ang, &sn, &cs);
  __syncthreads();
  p[lane] = (bf16_t)(x1 * cs - x2 * sn);
  p[lane + 64] = (bf16_t)(x1 * sn + x2 * cs);
}

// ---------------- flash attention, 32x32 swapped-QK^T ----------------
// grid 512 = B*H*(S/128); block 256 = 4 waves; wave owns 32 q-rows; KVBLK=64.
__global__ __launch_bounds__(256, 2) void attn_kernel(
    const bf16_t* __restrict__ Q, const bf16_t* __restrict__ Kr,
    const bf16_t* __restrict__ Vt, const int* __restrict__ mask,
    bf16_t* __restrict__ AO) {
  __shared__ float mbias[Sc];      // per-kv mask bias, 8 KB
  __shared__ float bcast[4][32];   // per-warp q-indexed broadcast
  const int tid = threadIdx.x;
  const int w = tid >> 6, lane = tid & 63;
  const int l31 = lane & 31, hi = lane >> 5;

  // bijective XCD swizzle: 64 consecutive logical blocks (4 full (b,h) groups) per XCD
  const int bid = blockIdx.x;
  const int L = ((bid & 7) << 6) + (bid >> 3);
  const int qc = L & 15, h = (L >> 4) & 15, b = L >> 8;

  const int* mb = mask + b * Sc;
#pragma unroll
  for (int i = 0; i < Sc / 256; ++i)
    mbias[i * 256 + tid] = mb[i * 256 + tid] ? 0.f : -1e9f;
  __syncthreads();

  const int q0 = qc * 128 + w * 32;
  const bf16_t* qb = Q + ((size_t)(b * Hc + h) * Sc + q0) * HDc;
  const bf16_t* kb = Kr + ((size_t)(b * Hc + h) * Sc) * HDc;
  const bf16_t* vb = Vt + ((size_t)(b * Hc + h) * HDc) * Sc;

  // Q fragments (B-operand): lane holds Q[q0+l31][k-slices]
  bf16x8 qf[8];
  {
    const bf16_t* qr = qb + (size_t)l31 * HDc + hi * 8;
#pragma unroll
    for (int kk = 0; kk < 8; ++kk) qf[kk] = *(const bf16x8*)(qr + kk * 16);
  }

  f32x16 acc[4];
#pragma unroll
  for (int d = 0; d < 4; ++d) acc[d] = 0.f;
  float mrun = -3.0e38f, lrun = 0.f;
  const float scale = 0.08838834764831845f;

  for (int kv0 = 0; kv0 < Sc; kv0 += 64) {
    // ---- QK^T: two 32-kv blocks, swapped operands (A=K, B=Q) ----
    f32x16 s0 = 0.f, s1 = 0.f;
    {
      const bf16_t* kr = kb + (size_t)(kv0 + l31) * HDc + hi * 8;
#pragma unroll
      for (int kk = 0; kk < 8; ++kk) {
        s0 = mfma32(*(const bf16x8*)(kr + kk * 16), qf[kk], s0);
        s1 = mfma32(*(const bf16x8*)(kr + 32 * HDc + kk * 16), qf[kk], s1);
      }
    }
    // ---- scale + mask bias; v[r] = S[q=l31][kv0 + (r<16?0:32) + crow(r&15,hi)] ----
    float v[32];
    {
      const float* mp = mbias + kv0 + 4 * hi;
#pragma unroll
      for (int g4 = 0; g4 < 4; ++g4) {
        f32x4 b0 = *(const f32x4*)(mp + 8 * g4);
        f32x4 b1 = *(const f32x4*)(mp + 32 + 8 * g4);
#pragma unroll
        for (int j = 0; j < 4; ++j) {
          v[g4 * 4 + j] = s0[g4 * 4 + j] * scale + b0[j];
          v[16 + g4 * 4 + j] = s1[g4 * 4 + j] * scale + b1[j];
        }
      }
    }
    // ---- tile max (in-lane + cross-half) ----
    float tm = v[0];
#pragma unroll
    for (int r = 1; r < 32; ++r) tm = fmaxf(tm, v[r]);
    tm = fmaxf(tm, __shfl_xor(tm, 32));
    // ---- defer-max rescale (rare) ----
    if (__any(tm > mrun + 8.f)) {
      float mnew = fmaxf(mrun, tm);
      float al = __expf(mrun - mnew);
      mrun = mnew;
      lrun *= al;
      bcast[w][l31] = al;  // halves write identical values
      asm volatile("s_waitcnt lgkmcnt(0)" ::: "memory");
      __builtin_amdgcn_sched_barrier(0);
#pragma unroll
      for (int g4 = 0; g4 < 4; ++g4) {
        f32x4 alr = *(const f32x4*)(&bcast[w][8 * g4 + 4 * hi]);
#pragma unroll
        for (int dblk = 0; dblk < 4; ++dblk)
#pragma unroll
          for (int j = 0; j < 4; ++j) acc[dblk][g4 * 4 + j] *= alr[j];
      }
    }
    // ---- P = exp(v - m), row sum ----
    float ts = 0.f;
#pragma unroll
    for (int r = 0; r < 32; ++r) {
      v[r] = __expf(v[r] - mrun);
      ts += v[r];
    }
    ts += __shfl_xor(ts, 32);
    lrun += ts;
    // ---- pack P -> PV A-fragments via cvt_pk + permlane32_swap ----
    unsigned pk[4][4];
#pragma unroll
    for (int ks = 0; ks < 4; ++ks) {
      unsigned a1 = cvtpk(v[ks * 8 + 0], v[ks * 8 + 1]);
      unsigned b1 = cvtpk(v[ks * 8 + 4], v[ks * 8 + 5]);
      unsigned a2 = cvtpk(v[ks * 8 + 2], v[ks * 8 + 3]);
      unsigned b2 = cvtpk(v[ks * 8 + 6], v[ks * 8 + 7]);
      plswap(a1, b1);
      plswap(a2, b2);
      pk[ks][0] = a1; pk[ks][1] = a2; pk[ks][2] = b1; pk[ks][3] = b2;
    }
    // ---- PV: O[q][d] += P V, B-operand from V^T (contiguous) ----
#pragma unroll
    for (int ks = 0; ks < 4; ++ks) {
      bf16x8 pa = *(const bf16x8*)&pk[ks][0];
      const bf16_t* vr = vb + (size_t)l31 * Sc + kv0 + ks * 16 + hi * 8;
#pragma unroll
      for (int dblk = 0; dblk < 4; ++dblk) {
        bf16x8 vf = *(const bf16x8*)(vr + (size_t)dblk * 32 * Sc);
        acc[dblk] = mfma32(pa, vf, acc[dblk]);
      }
    }
  }

  // ---- epilogue: normalize (per-q broadcast) and store ----
  float inv = 1.f / lrun;
  bcast[w][l31] = inv;
  asm volatile("s_waitcnt lgkmcnt(0)" ::: "memory");
  __builtin_amdgcn_sched_barrier(0);
  bf16_t* ob = AO + ((size_t)b * Sc + q0) * Dc + h * HDc;
#pragma unroll
  for (int g4 = 0; g4 < 4; ++g4) {
    f32x4 ir = *(const f32x4*)(&bcast[w][8 * g4 + 4 * hi]);
#pragma unroll
    for (int j = 0; j < 4; ++j) {
      int q = 8 * g4 + 4 * hi + j;  // crow(r,hi), r = 4*g4+j
#pragma unroll
      for (int dblk = 0; dblk < 4; ++dblk)
        ob[(size_t)q * Dc + dblk * 32 + l31] = (bf16_t)(acc[dblk][g4 * 4 + j] * ir[j]);
    }
  }
}

#define MB(x) ((size_t)(x) << 20)

extern "C" void kernel_launch(void* const* d_in, const int* in_sizes, int n_in,
                              void* d_out, int out_size, void* d_ws, size_t ws_size,
                              hipStream_t stream) {
  const float* x = (const float*)d_in[0];
  const int* mask = (const int*)d_in[1];
  const float* wq = (const float*)d_in[2];
  const float* bq = (const float*)d_in[3];
  const float* wk = (const float*)d_in[4];
  const float* bk = (const float*)d_in[5];
  const float* wv = (const float*)d_in[6];
  const float* bv = (const float*)d_in[7];
  const float* wo = (const float*)d_in[8];
  const float* bo = (const float*)d_in[9];
  float* out = (float*)d_out;

  char* ws = (char*)d_ws;
  bf16_t* xb  = (bf16_t*)(ws + MB(0));
  bf16_t* wqT = (bf16_t*)(ws + MB(16));
  bf16_t* wkT = (bf16_t*)(ws + MB(24));
  bf16_t* wvT = (bf16_t*)(ws + MB(32));
  bf16_t* woT = (bf16_t*)(ws + MB(40));
  bf16_t* qbuf = (bf16_t*)(ws + MB(48));
  bf16_t* kbuf = (bf16_t*)(ws + MB(64));
  bf16_t* vtb  = (bf16_t*)(ws + MB(80));
  bf16_t* ao   = (bf16_t*)(ws + MB(96));

  cvt_bf16_kernel<<<8192, 256, 0, stream>>>(x, xb, (Mc * Dc) / 4);

  dim3 tg(64, 64), tb(32, 8);
  transpose_cvt_kernel<<<tg, tb, 0, stream>>>(wq, wqT);
  transpose_cvt_kernel<<<tg, tb, 0, stream>>>(wk, wkT);
  transpose_cvt_kernel<<<tg, tb, 0, stream>>>(wv, wvT);
  transpose_cvt_kernel<<<tg, tb, 0, stream>>>(wo, woT);

  dim3 gg(Dc / 128, Mc / 128);
  gemm_bt_kernel<0><<<gg, 256, 0, stream>>>(xb, wqT, bq, qbuf, Dc);
  gemm_bt_kernel<0><<<gg, 256, 0, stream>>>(xb, wkT, bk, kbuf, Dc);
  gemm_bt_kernel<1><<<gg, 256, 0, stream>>>(xb, wvT, bv, vtb, Dc);

  rope_kernel<<<(2 * Bc * Hc * Sc) / 4, 256, 0, stream>>>(qbuf);

  attn_kernel<<<Bc * Hc * (Sc / 128), 256, 0, stream>>>(qbuf, kbuf, vtb, mask, ao);

  gemm_bt_kernel<2><<<gg, 256, 0, stream>>>(ao, woT, bo, out, Dc);
}

// Round 3
// 310.767 us; speedup vs baseline: 2.3731x; 1.5775x over previous
//
#include <hip/hip_runtime.h>

#define Bc 2
#define Sc 2048
#define Dc 2048
#define Hc 16
#define HDc 128
#define Mc 4096

typedef __bf16 bf16_t;
typedef __bf16 bf16x4 __attribute__((ext_vector_type(4)));
typedef __bf16 bf16x8 __attribute__((ext_vector_type(8)));
typedef float f32x4 __attribute__((ext_vector_type(4)));
typedef float f32x16 __attribute__((ext_vector_type(16)));

__device__ __forceinline__ f32x4 mfma16(bf16x8 a, bf16x8 b, f32x4 c) {
  return __builtin_amdgcn_mfma_f32_16x16x32_bf16(a, b, c, 0, 0, 0);
}
__device__ __forceinline__ f32x16 mfma32(bf16x8 a, bf16x8 b, f32x16 c) {
  return __builtin_amdgcn_mfma_f32_32x32x16_bf16(a, b, c, 0, 0, 0);
}

typedef const unsigned __attribute__((address_space(1))) gu32_t;
typedef unsigned __attribute__((address_space(3))) lu32_t;

__device__ __forceinline__ void gload_lds16(const void* g, void* l) {
  gu32_t* gp = (gu32_t*)(unsigned long long)g;
  lu32_t* lp = (lu32_t*)(unsigned)(unsigned long long)l;
  __builtin_amdgcn_global_load_lds(gp, lp, 16, 0, 0);
}

__device__ __forceinline__ unsigned cvtpk(float lo, float hi_) {
  unsigned r;
  asm("v_cvt_pk_bf16_f32 %0, %1, %2" : "=v"(r) : "v"(lo), "v"(hi_));
  return r;
}
__device__ __forceinline__ void plswap(unsigned& a, unsigned& b) {
  asm volatile("v_permlane32_swap_b32 %0, %1" : "+v"(a), "+v"(b));
}

// ---------------- convert x: fp32 -> bf16 ----------------
__global__ void cvt_bf16_kernel(const float* __restrict__ in, bf16_t* __restrict__ out, int n4) {
  int i = blockIdx.x * blockDim.x + threadIdx.x;
  if (i < n4) {
    float4 v = ((const float4*)in)[i];
    bf16x4 o;
    o[0] = (bf16_t)v.x; o[1] = (bf16_t)v.y; o[2] = (bf16_t)v.z; o[3] = (bf16_t)v.w;
    ((bf16x4*)out)[i] = o;
  }
}

// ---------------- transpose-convert weight: (K,N) fp32 -> (N,K) bf16 ----------------
__global__ void transpose_cvt_kernel(const float* __restrict__ w, bf16_t* __restrict__ wt) {
  __shared__ float tile[32][33];
  const int tx = threadIdx.x, ty = threadIdx.y;
  const int n0 = blockIdx.x * 32, k0 = blockIdx.y * 32;
#pragma unroll
  for (int i = 0; i < 32; i += 8)
    tile[ty + i][tx] = w[(size_t)(k0 + ty + i) * Dc + n0 + tx];
  __syncthreads();
#pragma unroll
  for (int i = 0; i < 32; i += 8)
    wt[(size_t)(n0 + ty + i) * Dc + k0 + tx] = (bf16_t)tile[tx][ty + i];
}

// ---------------- GEMM: C(MxN) = A(MxK) @ Bt(NxK)^T + bias ----------------
template <int MODE>
__global__ __launch_bounds__(256) void gemm_bt_kernel(
    const bf16_t* __restrict__ A, const bf16_t* __restrict__ Bt,
    const float* __restrict__ bias, void* __restrict__ outp, const int K) {
  __shared__ __align__(16) bf16_t sA[128 * 64];
  __shared__ __align__(16) bf16_t sB[128 * 64];
  const int w = threadIdx.x >> 6, lane = threadIdx.x & 63;
  const int l15 = lane & 15, g = lane >> 4;
  const int m0 = blockIdx.y * 128, n0 = blockIdx.x * 128;

  f32x4 acc[4][4] = {};

  for (int k0 = 0; k0 < K; k0 += 64) {
#pragma unroll
    for (int p = 0; p < 4; ++p) {
      int s_ = (p * 4 + w) * 64 + lane;
      int row = s_ >> 3, ch = s_ & 7;
      int sch = (ch ^ (row & 7)) * 8;
      gload_lds16(A + (size_t)(m0 + row) * K + k0 + sch,
                  (char*)sA + (size_t)((p * 4 + w) * 64) * 16);
      gload_lds16(Bt + (size_t)(n0 + row) * K + k0 + sch,
                  (char*)sB + (size_t)((p * 4 + w) * 64) * 16);
    }
    asm volatile("s_waitcnt vmcnt(0)" ::: "memory");
    __syncthreads();

    const int wm = (w >> 1) * 64, wn = (w & 1) * 64;
#pragma unroll
    for (int ks = 0; ks < 2; ++ks) {
      bf16x8 af[4], bfr[4];
#pragma unroll
      for (int i = 0; i < 4; ++i) {
        int ra = wm + i * 16 + l15;
        int ca = ((ks * 4 + g) ^ (ra & 7)) * 16;
        af[i] = *(const bf16x8*)((const char*)sA + ra * 128 + ca);
        int rb = wn + i * 16 + l15;
        int cb = ((ks * 4 + g) ^ (rb & 7)) * 16;
        bfr[i] = *(const bf16x8*)((const char*)sB + rb * 128 + cb);
      }
#pragma unroll
      for (int mi = 0; mi < 4; ++mi)
#pragma unroll
        for (int ni = 0; ni < 4; ++ni)
          acc[mi][ni] = mfma16(af[mi], bfr[ni], acc[mi][ni]);
    }
    __syncthreads();
  }

  const int wm = (w >> 1) * 64, wn = (w & 1) * 64;
#pragma unroll
  for (int mi = 0; mi < 4; ++mi) {
#pragma unroll
    for (int ni = 0; ni < 4; ++ni) {
      int ncol = n0 + wn + ni * 16 + l15;
      float bv = bias[ncol];
#pragma unroll
      for (int r = 0; r < 4; ++r) {
        int mrow = m0 + wm + mi * 16 + g * 4 + r;
        float v = acc[mi][ni][r] + bv;
        if (MODE == 2) {
          ((float*)outp)[(size_t)mrow * Dc + ncol] = v;
        } else {
          int b = mrow >> 11, sq = mrow & (Sc - 1);
          int h = ncol >> 7, hd = ncol & (HDc - 1);
          if (MODE == 0)
            ((bf16_t*)outp)[(((size_t)(b * Hc + h) * Sc + sq) * HDc) + hd] = (bf16_t)v;
          else
            ((bf16_t*)outp)[(((size_t)(b * Hc + h) * HDc + hd) * Sc) + sq] = (bf16_t)v;
        }
      }
    }
  }
}

// ---------------- RoPE in-place on Q then K region (contiguous), (B,H,S,HD) ----------------
__global__ __launch_bounds__(256) void rope_kernel(bf16_t* __restrict__ qk) {
  const int w = threadIdx.x >> 6, lane = threadIdx.x & 63;
  const long row = (long)blockIdx.x * 4 + w;
  const int s = (int)(row & (Sc - 1));
  bf16_t* p = qk + row * HDc;
  float x1 = (float)p[2 * lane];
  float x2 = (float)p[2 * lane + 1];
  float freq = expf(-(float)lane * (9.210340371976184f / 64.0f));
  float ang = (float)s * freq;
  float sn, cs;
  sincosf(ang, &sn, &cs);
  __syncthreads();
  p[lane] = (bf16_t)(x1 * cs - x2 * sn);
  p[lane + 64] = (bf16_t)(x1 * sn + x2 * cs);
}

// ---------------- flash attention, 32x32 swapped-QK^T, LDS dbuf K/V ----------------
// grid 512 = B*H*(S/128); block 256 = 4 waves; wave owns 32 q-rows; KVBLK=64.
__global__ __launch_bounds__(256, 2) void attn_kernel(
    const bf16_t* __restrict__ Q, const bf16_t* __restrict__ Kr,
    const bf16_t* __restrict__ Vt, const int* __restrict__ mask,
    bf16_t* __restrict__ AO) {
  __shared__ __align__(16) bf16_t sK[2][64 * 128];  // [kv][d], row=256B=16 chunks
  __shared__ __align__(16) bf16_t sV[2][128 * 64];  // [d][kv], row=128B=8 chunks
  __shared__ float mbias[Sc];
  __shared__ float bcast[4][32];
  const int tid = threadIdx.x;
  const int w = tid >> 6, lane = tid & 63;
  const int l31 = lane & 31, hi = lane >> 5;
  const int wbase = w * 64;

  const int bid = blockIdx.x;
  const int L = ((bid & 7) << 6) + (bid >> 3);
  const int qc = L & 15, h = (L >> 4) & 15, b = L >> 8;

  const int* mb = mask + b * Sc;
#pragma unroll
  for (int i = 0; i < Sc / 256; ++i)
    mbias[i * 256 + tid] = mb[i * 256 + tid] ? 0.f : -1e9f;

  const int q0 = qc * 128 + w * 32;
  const bf16_t* qb = Q + ((size_t)(b * Hc + h) * Sc + q0) * HDc;
  const bf16_t* kb = Kr + ((size_t)(b * Hc + h) * Sc) * HDc;
  const bf16_t* vb = Vt + ((size_t)(b * Hc + h) * HDc) * Sc;

  bf16x8 qf[8];
  {
    const bf16_t* qr = qb + (size_t)l31 * HDc + hi * 8;
#pragma unroll
    for (int kk = 0; kk < 8; ++kk) qf[kk] = *(const bf16x8*)(qr + kk * 16);
  }

  // staging: source-side XOR swizzle (chunk ^= row&7), linear LDS dest
#define STAGE_KV(sKb, sVb, kv0_)                                            \
  {                                                                         \
    _Pragma("unroll") for (int p = 0; p < 4; ++p) {                         \
      int s_ = p * 256 + tid;                                               \
      int rk = s_ >> 4, ck = s_ & 15;                                       \
      gload_lds16(kb + (size_t)((kv0_) + rk) * HDc + ((ck ^ (rk & 7)) * 8), \
                  (char*)(sKb) + (size_t)(p * 256 + wbase) * 16);           \
      int rv = s_ >> 3, cv = s_ & 7;                                        \
      gload_lds16(vb + (size_t)rv * Sc + (kv0_) + ((cv ^ (rv & 7)) * 8),    \
                  (char*)(sVb) + (size_t)(p * 256 + wbase) * 16);           \
    }                                                                       \
  }

  bf16_t* sKc = &sK[0][0];
  bf16_t* sKn = &sK[1][0];
  bf16_t* sVc = &sV[0][0];
  bf16_t* sVn = &sV[1][0];

  STAGE_KV(sKc, sVc, 0);
  asm volatile("s_waitcnt vmcnt(0)" ::: "memory");
  __syncthreads();

  f32x16 acc[4];
#pragma unroll
  for (int d = 0; d < 4; ++d) acc[d] = 0.f;
  float mrun = -3.0e38f, lrun = 0.f;
  const float scale = 0.08838834764831845f;

  for (int kv0 = 0; kv0 < Sc; kv0 += 64) {
    if (kv0 + 64 < Sc) STAGE_KV(sKn, sVn, kv0 + 64);

    // ---- QK^T from LDS: A=K rows (l31, 32+l31), B=Q ----
    f32x16 s0 = 0.f, s1 = 0.f;
    {
      const char* kbase = (const char*)sKc;
      const int swz = ((l31 & 7) ^ hi) * 16;  // chunk 2kk+hi -> ((2kk+hi)^(r&7))*16
#pragma unroll
      for (int kk = 0; kk < 8; ++kk) {
        bf16x8 k0f = *(const bf16x8*)(kbase + l31 * 256 + (((2 * kk + hi) ^ (l31 & 7)) * 16));
        bf16x8 k1f = *(const bf16x8*)(kbase + (32 + l31) * 256 + (((2 * kk + hi) ^ (l31 & 7)) * 16));
        s0 = mfma32(k0f, qf[kk], s0);
        s1 = mfma32(k1f, qf[kk], s1);
      }
      (void)swz;
    }
    // ---- scale + mask bias ----
    float v[32];
    {
      const float* mp = mbias + kv0 + 4 * hi;
#pragma unroll
      for (int g4 = 0; g4 < 4; ++g4) {
        f32x4 b0 = *(const f32x4*)(mp + 8 * g4);
        f32x4 b1 = *(const f32x4*)(mp + 32 + 8 * g4);
#pragma unroll
        for (int j = 0; j < 4; ++j) {
          v[g4 * 4 + j] = s0[g4 * 4 + j] * scale + b0[j];
          v[16 + g4 * 4 + j] = s1[g4 * 4 + j] * scale + b1[j];
        }
      }
    }
    // ---- tile max ----
    float tm = v[0];
#pragma unroll
    for (int r = 1; r < 32; ++r) tm = fmaxf(tm, v[r]);
    tm = fmaxf(tm, __shfl_xor(tm, 32));
    // ---- defer-max rescale (rare) ----
    if (__any(tm > mrun + 8.f)) {
      float mnew = fmaxf(mrun, tm);
      float al = __expf(mrun - mnew);
      mrun = mnew;
      lrun *= al;
      bcast[w][l31] = al;
      asm volatile("s_waitcnt lgkmcnt(0)" ::: "memory");
      __builtin_amdgcn_sched_barrier(0);
#pragma unroll
      for (int g4 = 0; g4 < 4; ++g4) {
        f32x4 alr = *(const f32x4*)(&bcast[w][8 * g4 + 4 * hi]);
#pragma unroll
        for (int dblk = 0; dblk < 4; ++dblk)
#pragma unroll
          for (int j = 0; j < 4; ++j) acc[dblk][g4 * 4 + j] *= alr[j];
      }
    }
    // ---- P = exp(v - m), row sum ----
    float ts = 0.f;
#pragma unroll
    for (int r = 0; r < 32; ++r) {
      v[r] = __expf(v[r] - mrun);
      ts += v[r];
    }
    ts += __shfl_xor(ts, 32);
    lrun += ts;
    // ---- pack P -> PV A-fragments ----
    unsigned pk[4][4];
#pragma unroll
    for (int ks = 0; ks < 4; ++ks) {
      unsigned a1 = cvtpk(v[ks * 8 + 0], v[ks * 8 + 1]);
      unsigned b1 = cvtpk(v[ks * 8 + 4], v[ks * 8 + 5]);
      unsigned a2 = cvtpk(v[ks * 8 + 2], v[ks * 8 + 3]);
      unsigned b2 = cvtpk(v[ks * 8 + 6], v[ks * 8 + 7]);
      plswap(a1, b1);
      plswap(a2, b2);
      pk[ks][0] = a1; pk[ks][1] = a2; pk[ks][2] = b1; pk[ks][3] = b2;
    }
    // ---- PV from LDS V^T tile ----
    {
      const char* vbase = (const char*)sVc;
#pragma unroll
      for (int ks = 0; ks < 4; ++ks) {
        bf16x8 pa = *(const bf16x8*)&pk[ks][0];
#pragma unroll
        for (int dblk = 0; dblk < 4; ++dblk) {
          int d = dblk * 32 + l31;
          bf16x8 vf = *(const bf16x8*)(vbase + d * 128 + (((2 * ks + hi) ^ (d & 7)) * 16));
          acc[dblk] = mfma32(pa, vf, acc[dblk]);
        }
      }
    }
    // ---- next tile staged? drain + flip ----
    asm volatile("s_waitcnt vmcnt(0)" ::: "memory");
    __syncthreads();
    bf16_t* t1 = sKc; sKc = sKn; sKn = t1;
    bf16_t* t2 = sVc; sVc = sVn; sVn = t2;
  }

  // ---- epilogue ----
  float inv = 1.f / lrun;
  bcast[w][l31] = inv;
  asm volatile("s_waitcnt lgkmcnt(0)" ::: "memory");
  __builtin_amdgcn_sched_barrier(0);
  bf16_t* ob = AO + ((size_t)b * Sc + q0) * Dc + h * HDc;
#pragma unroll
  for (int g4 = 0; g4 < 4; ++g4) {
    f32x4 ir = *(const f32x4*)(&bcast[w][8 * g4 + 4 * hi]);
#pragma unroll
    for (int j = 0; j < 4; ++j) {
      int q = 8 * g4 + 4 * hi + j;
#pragma unroll
      for (int dblk = 0; dblk < 4; ++dblk)
        ob[(size_t)q * Dc + dblk * 32 + l31] = (bf16_t)(acc[dblk][g4 * 4 + j] * ir[j]);
    }
  }
}

#define MB(x) ((size_t)(x) << 20)

extern "C" void kernel_launch(void* const* d_in, const int* in_sizes, int n_in,
                              void* d_out, int out_size, void* d_ws, size_t ws_size,
                              hipStream_t stream) {
  const float* x = (const float*)d_in[0];
  const int* mask = (const int*)d_in[1];
  const float* wq = (const float*)d_in[2];
  const float* bq = (const float*)d_in[3];
  const float* wk = (const float*)d_in[4];
  const float* bk = (const float*)d_in[5];
  const float* wv = (const float*)d_in[6];
  const float* bv = (const float*)d_in[7];
  const float* wo = (const float*)d_in[8];
  const float* bo = (const float*)d_in[9];
  float* out = (float*)d_out;

  char* ws = (char*)d_ws;
  bf16_t* xb  = (bf16_t*)(ws + MB(0));
  bf16_t* wqT = (bf16_t*)(ws + MB(16));
  bf16_t* wkT = (bf16_t*)(ws + MB(24));
  bf16_t* wvT = (bf16_t*)(ws + MB(32));
  bf16_t* woT = (bf16_t*)(ws + MB(40));
  bf16_t* qbuf = (bf16_t*)(ws + MB(48));
  bf16_t* kbuf = (bf16_t*)(ws + MB(64));
  bf16_t* vtb  = (bf16_t*)(ws + MB(80));
  bf16_t* ao   = (bf16_t*)(ws + MB(96));

  cvt_bf16_kernel<<<8192, 256, 0, stream>>>(x, xb, (Mc * Dc) / 4);

  dim3 tg(64, 64), tb(32, 8);
  transpose_cvt_kernel<<<tg, tb, 0, stream>>>(wq, wqT);
  transpose_cvt_kernel<<<tg, tb, 0, stream>>>(wk, wkT);
  transpose_cvt_kernel<<<tg, tb, 0, stream>>>(wv, wvT);
  transpose_cvt_kernel<<<tg, tb, 0, stream>>>(wo, woT);

  dim3 gg(Dc / 128, Mc / 128);
  gemm_bt_kernel<0><<<gg, 256, 0, stream>>>(xb, wqT, bq, qbuf, Dc);
  gemm_bt_kernel<0><<<gg, 256, 0, stream>>>(xb, wkT, bk, kbuf, Dc);
  gemm_bt_kernel<1><<<gg, 256, 0, stream>>>(xb, wvT, bv, vtb, Dc);

  rope_kernel<<<(2 * Bc * Hc * Sc) / 4, 256, 0, stream>>>(qbuf);

  attn_kernel<<<Bc * Hc * (Sc / 128), 256, 0, stream>>>(qbuf, kbuf, vtb, mask, ao);

  gemm_bt_kernel<2><<<gg, 256, 0, stream>>>(ao, woT, bo, out, Dc);
}